// Round 6
// baseline (3850.100 us; speedup 1.0000x reference)
//
#include <hip/hip_runtime.h>
#include <hip/hip_bf16.h>

#define BDIM 64
#define TDIM 360
#define BT (BDIM*TDIM)        // 23040
#define CDIM 128
#define HWSZ 1024
#define SDIM 64
#define G4 512
#define KTOP 160

typedef __hip_bfloat16 bf16;

static __device__ __forceinline__ unsigned int f2bu(float x) {
    bf16 b = __float2bfloat16(x);
    unsigned short u; __builtin_memcpy(&u, &b, 2); return (unsigned int)u;
}
static __device__ __forceinline__ float b2f(bf16 x) { return __bfloat162float(x); }
static __device__ __forceinline__ float tanh_fast(float x) {
    float e = __expf(2.0f * x);
    return 1.0f - 2.0f / (e + 1.0f);
}
static __device__ __forceinline__ float sigm(float x) {
    return 1.0f / (1.0f + __expf(-x));
}

// ---- static device workspace (~87 MB) ----
__device__ float        g_ArowsF[BT * KTOP];   // [x_emb(32) | in_seq(128)] fp32
__device__ float        g_pre2[BT * G4];       // precomputed non-recurrent gate part
__device__ unsigned int g_wpack[128 * G4];     // folded recurrent weights, bf16 pairs
__device__ float        g_penc[BDIM * SDIM * 64];
__device__ float        g_hatt[BT * 256];      // [h(128) | att(128)] per (b,t)
__device__ float        g_Wao[256 * 5];
__device__ float        g_bao[5];
__device__ float        g_bias[G4];
__device__ float        g_c0[G4];

// ---- A1: build [x_emb | gathered feature] rows (f32 in, f32 out) ----
__global__ void kA1(const float* __restrict__ tok, const float* __restrict__ feat,
                    const float* __restrict__ Wemb, const float* __restrict__ bemb) {
    int row  = blockIdx.x * 4 + (threadIdx.x >> 6);
    int lane = threadIdx.x & 63;
    const float* tp = tok + (size_t)row * 4;
    float t0 = tp[0], t1 = tp[1], t2 = tp[2], t3 = tp[3];
    int b = row / TDIM;
    int x = (int)(t0 * 100.0f);
    int y = (int)(t1 * 100.0f);
    x = min(max(x, 0), 31);
    y = min(max(y, 0), 31);
    int idx = y * 32 + x;                       // y*H + x, H=32
    float* out = g_ArowsF + (size_t)row * KTOP;
    if (lane < 32) {
        float e = t0 * Wemb[lane] + t1 * Wemb[32 + lane] +
                  t2 * Wemb[64 + lane] + t3 * Wemb[96 + lane] + bemb[lane];
        out[lane] = e;
    }
    const float* fb = feat + (size_t)b * CDIM * HWSZ + idx;
    out[32 + lane]      = fb[(size_t)lane * HWSZ];
    out[32 + 64 + lane] = fb[(size_t)(64 + lane) * HWSZ];
}

// ---- A2a: fold recurrent weights ----
__global__ void kA2a(const float* __restrict__ Wih, const float* __restrict__ Whh,
                     const float* __restrict__ Waap) {
    __shared__ float sa0[128], sa1[128];
    int p = blockIdx.x, n = threadIdx.x;
    int r0 = 2 * p, r1 = 2 * p + 1;
    if (n < 128)            sa0[n]        = Waap[r0 * 128 + n];
    else if (n < 256)       sa1[n - 128]  = Waap[r1 * 128 + (n - 128)];
    __syncthreads();
    float acc0 = (r0 < 128) ? Whh[r0 * G4 + n] : 0.0f;
    float acc1 = (r1 < 128) ? Whh[r1 * G4 + n] : 0.0f;
    for (int j = 0; j < 128; ++j) {
        float wi = Wih[(160 + j) * G4 + n];
        acc0 += sa0[j] * wi;
        acc1 += sa1[j] * wi;
    }
    g_wpack[p * G4 + n] = f2bu(acc0) | (f2bu(acc1) << 16);
}

// ---- A2c: bias vectors, c0, Wao, bao ----
__global__ void kA2c(const float* __restrict__ bih, const float* __restrict__ bhh,
                     const float* __restrict__ Wih, const float* __restrict__ Waap,
                     const float* __restrict__ baap, const float* __restrict__ Wout,
                     const float* __restrict__ bout) {
    __shared__ float sb[128];
    int n = threadIdx.x;
    if (n < 128) sb[n] = baap[n];
    __syncthreads();
    g_bias[n] = bih[n] + bhh[n];
    float c0 = 0.0f;
    for (int j = 0; j < 128; ++j) c0 += sb[j] * Wih[(160 + j) * G4 + n];
    g_c0[n] = c0;
    if (n < 256) {
        for (int o = 0; o < 5; ++o) {
            float acc = 0.0f;
            for (int j = 0; j < 128; ++j) acc += Waap[n * 128 + j] * Wout[j * 5 + o];
            g_Wao[n * 5 + o] = acc;
        }
    }
    if (n == 0) {
        for (int o = 0; o < 5; ++o) {
            float acc = bout[o];
            for (int j = 0; j < 128; ++j) acc += sb[j] * Wout[j * 5 + o];
            g_bao[o] = acc;
        }
    }
}

// ---- A2d: p_enc ----
__global__ void kA2d(const float* __restrict__ FH, const float* __restrict__ Wep,
                     const float* __restrict__ bep) {
    __shared__ float sfh[128 * 64];
    int b = blockIdx.x, tid = threadIdx.x;
    for (int i = tid; i < 128 * 64; i += 256) sfh[i] = FH[(size_t)b * 128 * 64 + i];
    __syncthreads();
    int a = tid & 63, sg = tid >> 6;
    float bias = bep[a];
    float acc[16];
#pragma unroll
    for (int i = 0; i < 16; ++i) acc[i] = bias;
    for (int d = 0; d < 128; ++d) {
        float wa = Wep[d * 64 + a];
#pragma unroll
        for (int i = 0; i < 16; ++i) acc[i] += sfh[d * 64 + sg * 16 + i] * wa;
    }
    for (int i = 0; i < 16; ++i)
        g_penc[((size_t)b * 64 + sg * 16 + i) * 64 + a] = acc[i];
}

// ---- B: pre2 = Arows @ W_ih[0:160]; 2 K-passes of 80 regs, 8 rows/block ----
__global__ void __attribute__((amdgpu_flat_work_group_size(512, 512),
                               amdgpu_waves_per_eu(2, 2)))
kB(const float* __restrict__ Wih) {
    int n = threadIdx.x;
    int m0 = blockIdx.x * 8;
    float racc[8];
#pragma unroll
    for (int r = 0; r < 8; ++r) racc[r] = 0.0f;
#pragma unroll 1
    for (int pass = 0; pass < 2; ++pass) {
        float wcol[80];
#pragma unroll
        for (int j = 0; j < 80; ++j) wcol[j] = Wih[(pass * 80 + j) * G4 + n];
#pragma unroll
        for (int r = 0; r < 8; ++r) {
            const float4* rp = (const float4*)(g_ArowsF + (size_t)(m0 + r) * KTOP + pass * 80);
            float a0 = 0.f, a1 = 0.f, a2 = 0.f, a3 = 0.f;
#pragma unroll
            for (int q = 0; q < 20; ++q) {
                float4 v = rp[q];
                a0 += wcol[4 * q + 0] * v.x;
                a1 += wcol[4 * q + 1] * v.y;
                a2 += wcol[4 * q + 2] * v.z;
                a3 += wcol[4 * q + 3] * v.w;
            }
            racc[r] += (a0 + a1) + (a2 + a3);
        }
    }
#pragma unroll
    for (int r = 0; r < 8; ++r)
        g_pre2[(size_t)(m0 + r) * G4 + n] = racc[r];
}

// ---- C: sequential recurrence, 1024 threads/block, K-split gate dot ----
// waves_per_eu(4,4) -> 128-VGPR cap (one 16-wave block per CU).
// Dot loop: 4 groups of 8 with sched_barrier(0) between groups so the
// scheduler can't hoist all 32 ds_read_b128 (round-5 lesson: full-unroll
// hoisting pushed demand to ~220 regs; allocator gave up -> 64 VGPRs +
// remat of all weight loads from L2 every step). Live set now
// wreg[64] + 8 float4 + accs ~ 105 <= 128 -> weights stay resident.
__global__ void __attribute__((amdgpu_flat_work_group_size(1024, 1024),
                               amdgpu_waves_per_eu(4, 4)))
kC(const float* __restrict__ FH,
   const float* __restrict__ W2a,
   const float* __restrict__ Walpha,
   const float* __restrict__ balpha,
   const float* __restrict__ bh2a) {
    __shared__ __align__(16) float s_val[256];   // [h(128) | att(128)]
    __shared__ float s_c[128];
    __shared__ float s_scratch[1024];            // dot partials / gates / reduction scratch
    __shared__ float s_atth[64];
    __shared__ float s_scores[64];
    __shared__ float s_wgt[64];
    __shared__ float s_walpha[64];
    __shared__ float s_bh2a[64];
    __shared__ float s_penc[64 * 65];            // padded stride 65
    __shared__ bf16  s_encp[128 * 70];           // enc[d][s], padded stride 70
    __shared__ bf16  s_w2a[128 * 64];

    int tid = threadIdx.x;
    int b = blockIdx.x;
    int kh = tid >> 9;            // K-half (0/1)
    int n  = tid & 511;           // gate output

    unsigned int wreg[64];
#pragma unroll
    for (int j = 0; j < 64; ++j) wreg[j] = g_wpack[(kh * 64 + j) * G4 + n];

    float bias_r = g_bias[n];
    float c0_r   = g_c0[n];

    if (tid < 256) s_val[tid] = 0.0f;
    if (tid < 128) s_c[tid] = 0.0f;
    if (tid < 64) { s_walpha[tid] = Walpha[tid]; s_bh2a[tid] = bh2a[tid]; }
    for (int i = tid; i < 64 * 64; i += 1024) {
        int s = i >> 6, a = i & 63;
        s_penc[s * 65 + a] = g_penc[((size_t)b * 64 + s) * 64 + a];
    }
    for (int i = tid; i < 128 * 64; i += 1024) {
        int d = i >> 6, s = i & 63;
        s_encp[d * 70 + s] = __float2bfloat16(FH[(size_t)b * 128 * 64 + i]);
        s_w2a[i] = __float2bfloat16(W2a[i]);
    }
    float bal = balpha[0];

    const float* pre2p = g_pre2 + (size_t)b * TDIM * G4 + n;
    float* hattp = g_hatt + (size_t)b * TDIM * 256;

    for (int t = 0; t < TDIM; ++t) {
        __syncthreads();                       // s_val (h_{t-1}, att_{t-1}) ready
        float pre2v = (tid < 512) ? pre2p[(size_t)t * G4] : 0.0f;
        // gate dot, K-half kh: 4 groups of 8, sched_barrier caps hoisting
        float acc0 = 0.f, acc1 = 0.f;
        const float4* vals = (const float4*)(s_val + kh * 128);
#pragma unroll
        for (int g = 0; g < 4; ++g) {
#pragma unroll
            for (int qq = 0; qq < 8; ++qq) {
                int q = g * 8 + qq;            // compile-time constant after unroll
                float4 v = vals[q];
                unsigned int w0 = wreg[2 * q], w1 = wreg[2 * q + 1];
                acc0 += __uint_as_float(w0 << 16)          * v.x;
                acc1 += __uint_as_float(w0 & 0xffff0000u)  * v.y;
                acc0 += __uint_as_float(w1 << 16)          * v.z;
                acc1 += __uint_as_float(w1 & 0xffff0000u)  * v.w;
            }
            __builtin_amdgcn_sched_barrier(0);
        }
        s_scratch[tid] = acc0 + acc1;
        __syncthreads();
        if (tid < 512) {
            float g = s_scratch[tid] + s_scratch[tid + 512] + pre2v + bias_r
                      + (t ? c0_r : 0.0f);
            s_scratch[tid] = g;
        }
        __syncthreads();
        // LSTM pointwise (gate order i,f,g,o)
        if (tid < 128) {
            float si = sigm(s_scratch[tid]);
            float sf = sigm(s_scratch[128 + tid]);
            float tg = tanh_fast(s_scratch[256 + tid]);
            float so = sigm(s_scratch[384 + tid]);
            float c = sf * s_c[tid] + si * tg;
            s_c[tid] = c;
            float h = so * tanh_fast(c);
            s_val[tid] = h;
            hattp[(size_t)t * 256 + tid] = h;
        }
        __syncthreads();
        // att_h = h @ W_h2att  (16 sub-groups of 8 k each)
        {
            int a = tid & 63, sub = tid >> 6;
            float acc = 0.f;
#pragma unroll
            for (int j = 0; j < 8; ++j) {
                int k = sub * 8 + j;
                acc += s_val[k] * b2f(s_w2a[k * 64 + a]);
            }
            s_scratch[sub * 64 + a] = acc;
        }
        __syncthreads();
        if (tid < 64) {
            float acc = s_bh2a[tid];
#pragma unroll
            for (int sub = 0; sub < 16; ++sub) acc += s_scratch[sub * 64 + tid];
            s_atth[tid] = acc;
        }
        __syncthreads();
        // scores[s] = sum_a tanh(p_enc + att_h) * W_alpha   (16 lanes per s, 4 a each)
        {
            int ss = tid >> 4, sub = tid & 15;
            float acc = 0.f;
#pragma unroll
            for (int j = 0; j < 4; ++j) {
                int a = sub * 4 + j;
                float xv = s_penc[ss * 65 + a] + s_atth[a];
                acc += tanh_fast(xv) * s_walpha[a];
            }
            acc += __shfl_xor(acc, 1);
            acc += __shfl_xor(acc, 2);
            acc += __shfl_xor(acc, 4);
            acc += __shfl_xor(acc, 8);
            if (sub == 0) s_scores[ss] = acc + bal;
        }
        __syncthreads();
        if (tid < 64) {
            float v = s_scores[tid];
            float m = v;
#pragma unroll
            for (int off = 32; off > 0; off >>= 1) m = fmaxf(m, __shfl_xor(m, off));
            float e = __expf(v - m);
            float sum = e;
#pragma unroll
            for (int off = 32; off > 0; off >>= 1) sum += __shfl_xor(sum, off);
            s_wgt[tid] = e / sum;
        }
        __syncthreads();
        // att_res[d] = sum_s wgt[s] * enc[s,d]   (8 groups of 8 s each)
        {
            int d = tid & 127, sc = tid >> 7;
            float acc = 0.f;
#pragma unroll
            for (int j = 0; j < 8; ++j) {
                int s5 = sc * 8 + j;
                acc += s_wgt[s5] * b2f(s_encp[d * 70 + s5]);
            }
            s_scratch[sc * 128 + d] = acc;
        }
        __syncthreads();
        if (tid < 128) {
            float att = 0.f;
#pragma unroll
            for (int sc = 0; sc < 8; ++sc) att += s_scratch[sc * 128 + tid];
            s_val[128 + tid] = att;
            hattp[(size_t)t * 256 + 128 + tid] = att;
        }
        // loop-top barrier covers s_val reuse
    }
}

// ---- D: final out = [h|att] @ (W_aap@W_out) + bao, f32 output ----
__global__ void kD(float* __restrict__ out) {
    int r = blockIdx.x, lane = threadIdx.x;
    const float4* hv = (const float4*)(g_hatt + (size_t)r * 256);
    float4 v = hv[lane];
    int k0 = lane * 4;
    float acc[5];
#pragma unroll
    for (int o = 0; o < 5; ++o)
        acc[o] = v.x * g_Wao[(k0 + 0) * 5 + o] + v.y * g_Wao[(k0 + 1) * 5 + o] +
                 v.z * g_Wao[(k0 + 2) * 5 + o] + v.w * g_Wao[(k0 + 3) * 5 + o];
#pragma unroll
    for (int off = 32; off > 0; off >>= 1) {
#pragma unroll
        for (int o = 0; o < 5; ++o) acc[o] += __shfl_xor(acc[o], off);
    }
    if (lane == 0) {
#pragma unroll
        for (int o = 0; o < 5; ++o) out[(size_t)r * 5 + o] = acc[o] + g_bao[o];
    }
}

extern "C" void kernel_launch(void* const* d_in, const int* in_sizes, int n_in,
                              void* d_out, int out_size, void* d_ws, size_t ws_size,
                              hipStream_t stream) {
    (void)in_sizes; (void)n_in; (void)d_ws; (void)ws_size; (void)out_size;
    const float* tok  = (const float*)d_in[0];
    const float* feat = (const float*)d_in[1];
    const float* FH   = (const float*)d_in[2];
    const float* Wemb = (const float*)d_in[3];
    const float* bemb = (const float*)d_in[4];
    const float* Wih  = (const float*)d_in[5];
    const float* bih  = (const float*)d_in[6];
    const float* Whh  = (const float*)d_in[7];
    const float* bhh  = (const float*)d_in[8];
    const float* W2a  = (const float*)d_in[9];
    const float* bh2a = (const float*)d_in[10];
    const float* Wal  = (const float*)d_in[11];
    const float* bal  = (const float*)d_in[12];
    const float* Wep  = (const float*)d_in[13];
    const float* bep  = (const float*)d_in[14];
    const float* Waap = (const float*)d_in[15];
    const float* baap = (const float*)d_in[16];
    const float* Wout = (const float*)d_in[17];
    const float* bout = (const float*)d_in[18];
    float* out = (float*)d_out;

    kA1<<<dim3(BT / 4), dim3(256), 0, stream>>>(tok, feat, Wemb, bemb);
    kA2a<<<dim3(128), dim3(512), 0, stream>>>(Wih, Whh, Waap);
    kA2c<<<dim3(1), dim3(512), 0, stream>>>(bih, bhh, Wih, Waap, baap, Wout, bout);
    kA2d<<<dim3(64), dim3(256), 0, stream>>>(FH, Wep, bep);
    kB<<<dim3(BT / 8), dim3(512), 0, stream>>>(Wih);
    kC<<<dim3(64), dim3(1024), 0, stream>>>(FH, W2a, Wal, bal, bh2a);
    kD<<<dim3(BT), dim3(64), 0, stream>>>(out);
}

// Round 7
// 2198.797 us; speedup vs baseline: 1.7510x; 1.7510x over previous
//
#include <hip/hip_runtime.h>
#include <hip/hip_bf16.h>

#define BDIM 64
#define TDIM 360
#define BT (BDIM*TDIM)        // 23040
#define CDIM 128
#define HWSZ 1024
#define SDIM 64
#define G4 512
#define KTOP 160

typedef __hip_bfloat16 bf16;

static __device__ __forceinline__ unsigned int f2bu(float x) {
    bf16 b = __float2bfloat16(x);
    unsigned short u; __builtin_memcpy(&u, &b, 2); return (unsigned int)u;
}
static __device__ __forceinline__ float b2f(bf16 x) { return __bfloat162float(x); }
static __device__ __forceinline__ float bl(unsigned int u) { return __uint_as_float(u << 16); }
static __device__ __forceinline__ float bh(unsigned int u) { return __uint_as_float(u & 0xffff0000u); }
static __device__ __forceinline__ float tanh_fast(float x) {
    float e = __expf(2.0f * x);
    return 1.0f - 2.0f / (e + 1.0f);
}
static __device__ __forceinline__ float sigm(float x) {
    return 1.0f / (1.0f + __expf(-x));
}

// ---- static device workspace ----
__device__ float        g_ArowsF[BT * KTOP];   // [x_emb(32) | in_seq(128)] fp32
__device__ float        g_pre2[BT * G4];       // precomputed non-recurrent gate part
// folded recurrent weights, bf16 pairs, streaming-friendly layout:
// u32 at ((jblk*1024 + (kh*512+n))*4 + jj) holds K-pair p = kh*64 + jblk*4 + jj
// (lo16 = K-even row 2p, hi16 = K-odd row 2p+1), column n.
// -> thread u = kh*512+n reads 16 lane-coalesced dwordx4 per step.
__device__ unsigned int g_wpk2[16 * 1024 * 4];
__device__ float        g_penc[BDIM * SDIM * 64];
__device__ float        g_hatt[BT * 256];      // [h(128) | att(128)] per (b,t)
__device__ float        g_Wao[256 * 5];
__device__ float        g_bao[5];
__device__ float        g_bias[G4];
__device__ float        g_c0[G4];

// ---- A1: build [x_emb | gathered feature] rows (f32 in, f32 out) ----
__global__ void kA1(const float* __restrict__ tok, const float* __restrict__ feat,
                    const float* __restrict__ Wemb, const float* __restrict__ bemb) {
    int row  = blockIdx.x * 4 + (threadIdx.x >> 6);
    int lane = threadIdx.x & 63;
    const float* tp = tok + (size_t)row * 4;
    float t0 = tp[0], t1 = tp[1], t2 = tp[2], t3 = tp[3];
    int b = row / TDIM;
    int x = (int)(t0 * 100.0f);
    int y = (int)(t1 * 100.0f);
    x = min(max(x, 0), 31);
    y = min(max(y, 0), 31);
    int idx = y * 32 + x;                       // y*H + x, H=32
    float* out = g_ArowsF + (size_t)row * KTOP;
    if (lane < 32) {
        float e = t0 * Wemb[lane] + t1 * Wemb[32 + lane] +
                  t2 * Wemb[64 + lane] + t3 * Wemb[96 + lane] + bemb[lane];
        out[lane] = e;
    }
    const float* fb = feat + (size_t)b * CDIM * HWSZ + idx;
    out[32 + lane]      = fb[(size_t)lane * HWSZ];
    out[32 + 64 + lane] = fb[(size_t)(64 + lane) * HWSZ];
}

// ---- A2a: fold recurrent weights into streaming layout ----
__global__ void kA2a(const float* __restrict__ Wih, const float* __restrict__ Whh,
                     const float* __restrict__ Waap) {
    __shared__ float sa0[128], sa1[128];
    int p = blockIdx.x, n = threadIdx.x;
    int r0 = 2 * p, r1 = 2 * p + 1;
    if (n < 128)            sa0[n]        = Waap[r0 * 128 + n];
    else if (n < 256)       sa1[n - 128]  = Waap[r1 * 128 + (n - 128)];
    __syncthreads();
    float acc0 = (r0 < 128) ? Whh[r0 * G4 + n] : 0.0f;
    float acc1 = (r1 < 128) ? Whh[r1 * G4 + n] : 0.0f;
    for (int j = 0; j < 128; ++j) {
        float wi = Wih[(160 + j) * G4 + n];
        acc0 += sa0[j] * wi;
        acc1 += sa1[j] * wi;
    }
    int kh = p >> 6, j = p & 63;
    int jblk = j >> 2, jj = j & 3;
    int u = kh * 512 + n;
    g_wpk2[((size_t)jblk * 1024 + u) * 4 + jj] = f2bu(acc0) | (f2bu(acc1) << 16);
}

// ---- A2c: bias vectors, c0, Wao, bao ----
__global__ void kA2c(const float* __restrict__ bih, const float* __restrict__ bhh,
                     const float* __restrict__ Wih, const float* __restrict__ Waap,
                     const float* __restrict__ baap, const float* __restrict__ Wout,
                     const float* __restrict__ bout) {
    __shared__ float sb[128];
    int n = threadIdx.x;
    if (n < 128) sb[n] = baap[n];
    __syncthreads();
    g_bias[n] = bih[n] + bhh[n];
    float c0 = 0.0f;
    for (int j = 0; j < 128; ++j) c0 += sb[j] * Wih[(160 + j) * G4 + n];
    g_c0[n] = c0;
    if (n < 256) {
        for (int o = 0; o < 5; ++o) {
            float acc = 0.0f;
            for (int j = 0; j < 128; ++j) acc += Waap[n * 128 + j] * Wout[j * 5 + o];
            g_Wao[n * 5 + o] = acc;
        }
    }
    if (n == 0) {
        for (int o = 0; o < 5; ++o) {
            float acc = bout[o];
            for (int j = 0; j < 128; ++j) acc += sb[j] * Wout[j * 5 + o];
            g_bao[o] = acc;
        }
    }
}

// ---- A2d: p_enc ----
__global__ void kA2d(const float* __restrict__ FH, const float* __restrict__ Wep,
                     const float* __restrict__ bep) {
    __shared__ float sfh[128 * 64];
    int b = blockIdx.x, tid = threadIdx.x;
    for (int i = tid; i < 128 * 64; i += 256) sfh[i] = FH[(size_t)b * 128 * 64 + i];
    __syncthreads();
    int a = tid & 63, sg = tid >> 6;
    float bias = bep[a];
    float acc[16];
#pragma unroll
    for (int i = 0; i < 16; ++i) acc[i] = bias;
    for (int d = 0; d < 128; ++d) {
        float wa = Wep[d * 64 + a];
#pragma unroll
        for (int i = 0; i < 16; ++i) acc[i] += sfh[d * 64 + sg * 16 + i] * wa;
    }
    for (int i = 0; i < 16; ++i)
        g_penc[((size_t)b * 64 + sg * 16 + i) * 64 + a] = acc[i];
}

// ---- B: pre2 = Arows @ W_ih[0:160]; 2 K-passes of 80 regs, 8 rows/block ----
__global__ void __attribute__((amdgpu_flat_work_group_size(512, 512),
                               amdgpu_waves_per_eu(2, 2)))
kB(const float* __restrict__ Wih) {
    int n = threadIdx.x;
    int m0 = blockIdx.x * 8;
    float racc[8];
#pragma unroll
    for (int r = 0; r < 8; ++r) racc[r] = 0.0f;
#pragma unroll 1
    for (int pass = 0; pass < 2; ++pass) {
        float wcol[80];
#pragma unroll
        for (int j = 0; j < 80; ++j) wcol[j] = Wih[(pass * 80 + j) * G4 + n];
#pragma unroll
        for (int r = 0; r < 8; ++r) {
            const float4* rp = (const float4*)(g_ArowsF + (size_t)(m0 + r) * KTOP + pass * 80);
            float a0 = 0.f, a1 = 0.f, a2 = 0.f, a3 = 0.f;
#pragma unroll
            for (int q = 0; q < 20; ++q) {
                float4 v = rp[q];
                a0 += wcol[4 * q + 0] * v.x;
                a1 += wcol[4 * q + 1] * v.y;
                a2 += wcol[4 * q + 2] * v.z;
                a3 += wcol[4 * q + 3] * v.w;
            }
            racc[r] += (a0 + a1) + (a2 + a3);
        }
    }
#pragma unroll
    for (int r = 0; r < 8; ++r)
        g_pre2[(size_t)(m0 + r) * G4 + n] = racc[r];
}

// Consume one uint4 (4 K-pairs) of weight block jb against vals[2jb],[2jb+1].
#define CONS1(W, jb) { \
    float4 v0 = vals[2 * (jb)], v1 = vals[2 * (jb) + 1]; \
    acc0 += bl(W.x) * v0.x;  acc1 += bh(W.x) * v0.y; \
    acc0 += bl(W.y) * v0.z;  acc1 += bh(W.y) * v0.w; \
    acc0 += bl(W.z) * v1.x;  acc1 += bh(W.z) * v1.y; \
    acc0 += bl(W.w) * v1.z;  acc1 += bh(W.w) * v1.w; }
#define LOADG(r0, r1, r2, r3, g) \
    r0 = wp[(g) * 4096]; r1 = wp[(g) * 4096 + 1024]; \
    r2 = wp[(g) * 4096 + 2048]; r3 = wp[(g) * 4096 + 3072];
#define CONSG(r0, r1, r2, r3, g) \
    CONS1(r0, (g) * 4 + 0) CONS1(r1, (g) * 4 + 1) \
    CONS1(r2, (g) * 4 + 2) CONS1(r3, (g) * 4 + 3)

// ---- C: sequential recurrence, 1024 threads/block ----
// Round-7 mechanism change: weights are STREAMED from L2 every step through an
// explicit 2-bank (A/B) pipeline of lane-coalesced dwordx4 loads, designed to
// live within the ~64-VGPR budget the allocator actually grants 1024-thread
// blocks (rounds 3-6: every attempt to keep 64+ weight regs resident was
// refused and remat'd with latency-serialized waits -> 9 us/step).
// In-flight window = 8 uint4 (32 regs); sched_barrier(0) after each consume
// stops the scheduler from collapsing the pipeline; counted vmcnt waits +
// 4 waves/SIMD hide the ~200-cyc L2 latency.
__global__ void __attribute__((amdgpu_flat_work_group_size(1024, 1024),
                               amdgpu_waves_per_eu(4, 4)))
kC(const float* __restrict__ FH,
   const float* __restrict__ W2a,
   const float* __restrict__ Walpha,
   const float* __restrict__ balpha,
   const float* __restrict__ bh2a) {
    __shared__ __align__(16) float s_val[256];   // [h(128) | att(128)]
    __shared__ float s_c[128];
    __shared__ float s_scratch[1024];            // dot partials / gates / reduction scratch
    __shared__ float s_atth[64];
    __shared__ float s_scores[64];
    __shared__ float s_wgt[64];
    __shared__ float s_walpha[64];
    __shared__ float s_bh2a[64];
    __shared__ float s_penc[64 * 65];            // padded stride 65
    __shared__ bf16  s_encp[128 * 70];           // enc[d][s], padded stride 70
    __shared__ bf16  s_w2a[128 * 64];

    int tid = threadIdx.x;
    int b = blockIdx.x;
    int kh = tid >> 9;            // K-half (0/1)
    int n  = tid & 511;           // gate output

    const uint4* wp = ((const uint4*)g_wpk2) + tid;   // u = kh*512+n == tid

    float bias_r = g_bias[n];
    float c0_r   = g_c0[n];

    if (tid < 256) s_val[tid] = 0.0f;
    if (tid < 128) s_c[tid] = 0.0f;
    if (tid < 64) { s_walpha[tid] = Walpha[tid]; s_bh2a[tid] = bh2a[tid]; }
    for (int i = tid; i < 64 * 64; i += 1024) {
        int s = i >> 6, a = i & 63;
        s_penc[s * 65 + a] = g_penc[((size_t)b * 64 + s) * 64 + a];
    }
    for (int i = tid; i < 128 * 64; i += 1024) {
        int d = i >> 6, s = i & 63;
        s_encp[d * 70 + s] = __float2bfloat16(FH[(size_t)b * 128 * 64 + i]);
        s_w2a[i] = __float2bfloat16(W2a[i]);
    }
    float bal = balpha[0];

    const float* pre2p = g_pre2 + (size_t)b * TDIM * G4 + n;
    float* hattp = g_hatt + (size_t)b * TDIM * 256;

    for (int t = 0; t < TDIM; ++t) {
        __syncthreads();                       // s_val (h_{t-1}, att_{t-1}) ready
        float pre2v = (tid < 512) ? pre2p[(size_t)t * G4] : 0.0f;
        // gate dot, K-half kh: stream 16 dwordx4 weights via A/B banks
        float acc0 = 0.f, acc1 = 0.f;
        const float4* vals = (const float4*)(s_val + kh * 128);
        {
            uint4 A0, A1, A2, A3, B0, B1, B2, B3;
            LOADG(A0, A1, A2, A3, 0)
            LOADG(B0, B1, B2, B3, 1)
            CONSG(A0, A1, A2, A3, 0)
            __builtin_amdgcn_sched_barrier(0);
            LOADG(A0, A1, A2, A3, 2)
            CONSG(B0, B1, B2, B3, 1)
            __builtin_amdgcn_sched_barrier(0);
            LOADG(B0, B1, B2, B3, 3)
            CONSG(A0, A1, A2, A3, 2)
            __builtin_amdgcn_sched_barrier(0);
            CONSG(B0, B1, B2, B3, 3)
        }
        s_scratch[tid] = acc0 + acc1;
        __syncthreads();
        if (tid < 512) {
            float g = s_scratch[tid] + s_scratch[tid + 512] + pre2v + bias_r
                      + (t ? c0_r : 0.0f);
            s_scratch[tid] = g;
        }
        __syncthreads();
        // LSTM pointwise (gate order i,f,g,o)
        if (tid < 128) {
            float si = sigm(s_scratch[tid]);
            float sf = sigm(s_scratch[128 + tid]);
            float tg = tanh_fast(s_scratch[256 + tid]);
            float so = sigm(s_scratch[384 + tid]);
            float c = sf * s_c[tid] + si * tg;
            s_c[tid] = c;
            float h = so * tanh_fast(c);
            s_val[tid] = h;
            hattp[(size_t)t * 256 + tid] = h;
        }
        __syncthreads();
        // att_h = h @ W_h2att  (16 sub-groups of 8 k each)
        {
            int a = tid & 63, sub = tid >> 6;
            float acc = 0.f;
#pragma unroll
            for (int j = 0; j < 8; ++j) {
                int k = sub * 8 + j;
                acc += s_val[k] * b2f(s_w2a[k * 64 + a]);
            }
            s_scratch[sub * 64 + a] = acc;
        }
        __syncthreads();
        if (tid < 64) {
            float acc = s_bh2a[tid];
#pragma unroll
            for (int sub = 0; sub < 16; ++sub) acc += s_scratch[sub * 64 + tid];
            s_atth[tid] = acc;
        }
        __syncthreads();
        // scores[s] = sum_a tanh(p_enc + att_h) * W_alpha   (16 lanes per s, 4 a each)
        {
            int ss = tid >> 4, sub = tid & 15;
            float acc = 0.f;
#pragma unroll
            for (int j = 0; j < 4; ++j) {
                int a = sub * 4 + j;
                float xv = s_penc[ss * 65 + a] + s_atth[a];
                acc += tanh_fast(xv) * s_walpha[a];
            }
            acc += __shfl_xor(acc, 1);
            acc += __shfl_xor(acc, 2);
            acc += __shfl_xor(acc, 4);
            acc += __shfl_xor(acc, 8);
            if (sub == 0) s_scores[ss] = acc + bal;
        }
        __syncthreads();
        if (tid < 64) {
            float v = s_scores[tid];
            float m = v;
#pragma unroll
            for (int off = 32; off > 0; off >>= 1) m = fmaxf(m, __shfl_xor(m, off));
            float e = __expf(v - m);
            float sum = e;
#pragma unroll
            for (int off = 32; off > 0; off >>= 1) sum += __shfl_xor(sum, off);
            s_wgt[tid] = e / sum;
        }
        __syncthreads();
        // att_res[d] = sum_s wgt[s] * enc[s,d]   (8 groups of 8 s each)
        {
            int d = tid & 127, sc = tid >> 7;
            float acc = 0.f;
#pragma unroll
            for (int j = 0; j < 8; ++j) {
                int s5 = sc * 8 + j;
                acc += s_wgt[s5] * b2f(s_encp[d * 70 + s5]);
            }
            s_scratch[sc * 128 + d] = acc;
        }
        __syncthreads();
        if (tid < 128) {
            float att = 0.f;
#pragma unroll
            for (int sc = 0; sc < 8; ++sc) att += s_scratch[sc * 128 + tid];
            s_val[128 + tid] = att;
            hattp[(size_t)t * 256 + 128 + tid] = att;
        }
        // loop-top barrier covers s_val reuse
    }
}

// ---- D: final out = [h|att] @ (W_aap@W_out) + bao, f32 output ----
__global__ void kD(float* __restrict__ out) {
    int r = blockIdx.x, lane = threadIdx.x;
    const float4* hv = (const float4*)(g_hatt + (size_t)r * 256);
    float4 v = hv[lane];
    int k0 = lane * 4;
    float acc[5];
#pragma unroll
    for (int o = 0; o < 5; ++o)
        acc[o] = v.x * g_Wao[(k0 + 0) * 5 + o] + v.y * g_Wao[(k0 + 1) * 5 + o] +
                 v.z * g_Wao[(k0 + 2) * 5 + o] + v.w * g_Wao[(k0 + 3) * 5 + o];
#pragma unroll
    for (int off = 32; off > 0; off >>= 1) {
#pragma unroll
        for (int o = 0; o < 5; ++o) acc[o] += __shfl_xor(acc[o], off);
    }
    if (lane == 0) {
#pragma unroll
        for (int o = 0; o < 5; ++o) out[(size_t)r * 5 + o] = acc[o] + g_bao[o];
    }
}

extern "C" void kernel_launch(void* const* d_in, const int* in_sizes, int n_in,
                              void* d_out, int out_size, void* d_ws, size_t ws_size,
                              hipStream_t stream) {
    (void)in_sizes; (void)n_in; (void)d_ws; (void)ws_size; (void)out_size;
    const float* tok  = (const float*)d_in[0];
    const float* feat = (const float*)d_in[1];
    const float* FH   = (const float*)d_in[2];
    const float* Wemb = (const float*)d_in[3];
    const float* bemb = (const float*)d_in[4];
    const float* Wih  = (const float*)d_in[5];
    const float* bih  = (const float*)d_in[6];
    const float* Whh  = (const float*)d_in[7];
    const float* bhh  = (const float*)d_in[8];
    const float* W2a  = (const float*)d_in[9];
    const float* bh2a = (const float*)d_in[10];
    const float* Wal  = (const float*)d_in[11];
    const float* bal  = (const float*)d_in[12];
    const float* Wep  = (const float*)d_in[13];
    const float* bep  = (const float*)d_in[14];
    const float* Waap = (const float*)d_in[15];
    const float* baap = (const float*)d_in[16];
    const float* Wout = (const float*)d_in[17];
    const float* bout = (const float*)d_in[18];
    float* out = (float*)d_out;

    kA1<<<dim3(BT / 4), dim3(256), 0, stream>>>(tok, feat, Wemb, bemb);
    kA2a<<<dim3(128), dim3(512), 0, stream>>>(Wih, Whh, Waap);
    kA2c<<<dim3(1), dim3(512), 0, stream>>>(bih, bhh, Wih, Waap, baap, Wout, bout);
    kA2d<<<dim3(64), dim3(256), 0, stream>>>(FH, Wep, bep);
    kB<<<dim3(BT / 8), dim3(512), 0, stream>>>(Wih);
    kC<<<dim3(64), dim3(1024), 0, stream>>>(FH, W2a, Wal, bal, bh2a);
    kD<<<dim3(BT), dim3(64), 0, stream>>>(out);
}

// Round 9
// 1848.781 us; speedup vs baseline: 2.0825x; 1.1893x over previous
//
#include <hip/hip_runtime.h>
#include <hip/hip_bf16.h>

#define BDIM 64
#define TDIM 360
#define BT (BDIM*TDIM)        // 23040
#define CDIM 128
#define HWSZ 1024
#define SDIM 64
#define G4 512
#define KTOP 160

typedef __hip_bfloat16 bf16;

static __device__ __forceinline__ unsigned int f2bu(float x) {
    bf16 b = __float2bfloat16(x);
    unsigned short u; __builtin_memcpy(&u, &b, 2); return (unsigned int)u;
}
static __device__ __forceinline__ float b2f(bf16 x) { return __bfloat162float(x); }
static __device__ __forceinline__ float bl(unsigned int u) { return __uint_as_float(u << 16); }
static __device__ __forceinline__ float bh(unsigned int u) { return __uint_as_float(u & 0xffff0000u); }
static __device__ __forceinline__ float tanh_fast(float x) {
    float e = __expf(2.0f * x);
    return 1.0f - 2.0f / (e + 1.0f);
}
static __device__ __forceinline__ float sigm(float x) {
    return 1.0f / (1.0f + __expf(-x));
}

// ---- static device workspace ----
__device__ float        g_ArowsF[BT * KTOP];   // [x_emb(32) | in_seq(128)] fp32
__device__ float        g_pre2[BT * G4];       // precomputed non-recurrent gate part
// folded recurrent weights, bf16 pairs, streaming layout (round 7):
// thread u = kh*512+n reads 16 lane-coalesced dwordx4 per step.
__device__ __align__(16) unsigned int g_wpk2[16 * 1024 * 4];
__device__ float        g_penc[BDIM * SDIM * 64];
__device__ float        g_hatt[BT * 256];      // [h(128) | att(128)] per (b,t)
__device__ float        g_Wao[256 * 5];
__device__ float        g_bao[5];
__device__ float        g_bias[G4];
__device__ float        g_c0[G4];

// ---- A1: build [x_emb | gathered feature] rows ----
__global__ void kA1(const float* __restrict__ tok, const float* __restrict__ feat,
                    const float* __restrict__ Wemb, const float* __restrict__ bemb) {
    int row  = blockIdx.x * 4 + (threadIdx.x >> 6);
    int lane = threadIdx.x & 63;
    const float* tp = tok + (size_t)row * 4;
    float t0 = tp[0], t1 = tp[1], t2 = tp[2], t3 = tp[3];
    int b = row / TDIM;
    int x = (int)(t0 * 100.0f);
    int y = (int)(t1 * 100.0f);
    x = min(max(x, 0), 31);
    y = min(max(y, 0), 31);
    int idx = y * 32 + x;
    float* out = g_ArowsF + (size_t)row * KTOP;
    if (lane < 32) {
        float e = t0 * Wemb[lane] + t1 * Wemb[32 + lane] +
                  t2 * Wemb[64 + lane] + t3 * Wemb[96 + lane] + bemb[lane];
        out[lane] = e;
    }
    const float* fb = feat + (size_t)b * CDIM * HWSZ + idx;
    out[32 + lane]      = fb[(size_t)lane * HWSZ];
    out[32 + 64 + lane] = fb[(size_t)(64 + lane) * HWSZ];
}

// ---- A2a: fold recurrent weights into streaming layout ----
__global__ void kA2a(const float* __restrict__ Wih, const float* __restrict__ Whh,
                     const float* __restrict__ Waap) {
    __shared__ float sa0[128], sa1[128];
    int p = blockIdx.x, n = threadIdx.x;
    int r0 = 2 * p, r1 = 2 * p + 1;
    if (n < 128)            sa0[n]        = Waap[r0 * 128 + n];
    else if (n < 256)       sa1[n - 128]  = Waap[r1 * 128 + (n - 128)];
    __syncthreads();
    float acc0 = (r0 < 128) ? Whh[r0 * G4 + n] : 0.0f;
    float acc1 = (r1 < 128) ? Whh[r1 * G4 + n] : 0.0f;
    for (int j = 0; j < 128; ++j) {
        float wi = Wih[(160 + j) * G4 + n];
        acc0 += sa0[j] * wi;
        acc1 += sa1[j] * wi;
    }
    int kh = p >> 6, j = p & 63;
    int jblk = j >> 2, jj = j & 3;
    int u = kh * 512 + n;
    g_wpk2[((size_t)jblk * 1024 + u) * 4 + jj] = f2bu(acc0) | (f2bu(acc1) << 16);
}

// ---- A2c: bias vectors, c0, Wao, bao ----
__global__ void kA2c(const float* __restrict__ bih, const float* __restrict__ bhh,
                     const float* __restrict__ Wih, const float* __restrict__ Waap,
                     const float* __restrict__ baap, const float* __restrict__ Wout,
                     const float* __restrict__ bout) {
    __shared__ float sb[128];
    int n = threadIdx.x;
    if (n < 128) sb[n] = baap[n];
    __syncthreads();
    g_bias[n] = bih[n] + bhh[n];
    float c0 = 0.0f;
    for (int j = 0; j < 128; ++j) c0 += sb[j] * Wih[(160 + j) * G4 + n];
    g_c0[n] = c0;
    if (n < 256) {
        for (int o = 0; o < 5; ++o) {
            float acc = 0.0f;
            for (int j = 0; j < 128; ++j) acc += Waap[n * 128 + j] * Wout[j * 5 + o];
            g_Wao[n * 5 + o] = acc;
        }
    }
    if (n == 0) {
        for (int o = 0; o < 5; ++o) {
            float acc = bout[o];
            for (int j = 0; j < 128; ++j) acc += sb[j] * Wout[j * 5 + o];
            g_bao[o] = acc;
        }
    }
}

// ---- A2d: p_enc ----
__global__ void kA2d(const float* __restrict__ FH, const float* __restrict__ Wep,
                     const float* __restrict__ bep) {
    __shared__ float sfh[128 * 64];
    int b = blockIdx.x, tid = threadIdx.x;
    for (int i = tid; i < 128 * 64; i += 256) sfh[i] = FH[(size_t)b * 128 * 64 + i];
    __syncthreads();
    int a = tid & 63, sg = tid >> 6;
    float bias = bep[a];
    float acc[16];
#pragma unroll
    for (int i = 0; i < 16; ++i) acc[i] = bias;
    for (int d = 0; d < 128; ++d) {
        float wa = Wep[d * 64 + a];
#pragma unroll
        for (int i = 0; i < 16; ++i) acc[i] += sfh[d * 64 + sg * 16 + i] * wa;
    }
    for (int i = 0; i < 16; ++i)
        g_penc[((size_t)b * 64 + sg * 16 + i) * 64 + a] = acc[i];
}

// ---- B: pre2 = Arows @ W_ih[0:160] ----
__global__ void __attribute__((amdgpu_flat_work_group_size(512, 512),
                               amdgpu_waves_per_eu(2, 2)))
kB(const float* __restrict__ Wih) {
    int n = threadIdx.x;
    int m0 = blockIdx.x * 8;
    float racc[8];
#pragma unroll
    for (int r = 0; r < 8; ++r) racc[r] = 0.0f;
#pragma unroll 1
    for (int pass = 0; pass < 2; ++pass) {
        float wcol[80];
#pragma unroll
        for (int j = 0; j < 80; ++j) wcol[j] = Wih[(pass * 80 + j) * G4 + n];
#pragma unroll
        for (int r = 0; r < 8; ++r) {
            const float4* rp = (const float4*)(g_ArowsF + (size_t)(m0 + r) * KTOP + pass * 80);
            float a0 = 0.f, a1 = 0.f, a2 = 0.f, a3 = 0.f;
#pragma unroll
            for (int q = 0; q < 20; ++q) {
                float4 v = rp[q];
                a0 += wcol[4 * q + 0] * v.x;
                a1 += wcol[4 * q + 1] * v.y;
                a2 += wcol[4 * q + 2] * v.z;
                a3 += wcol[4 * q + 3] * v.w;
            }
            racc[r] += (a0 + a1) + (a2 + a3);
        }
    }
#pragma unroll
    for (int r = 0; r < 8; ++r)
        g_pre2[(size_t)(m0 + r) * G4 + n] = racc[r];
}

#define CONS1(W, jb) { \
    float4 v0 = vals[2 * (jb)], v1 = vals[2 * (jb) + 1]; \
    acc0 += bl(W.x) * v0.x;  acc1 += bh(W.x) * v0.y; \
    acc0 += bl(W.y) * v0.z;  acc1 += bh(W.y) * v0.w; \
    acc0 += bl(W.z) * v1.x;  acc1 += bh(W.z) * v1.y; \
    acc0 += bl(W.w) * v1.z;  acc1 += bh(W.w) * v1.w; }
#define LOADG(r0, r1, r2, r3, g) \
    r0 = wp[(g) * 4096]; r1 = wp[(g) * 4096 + 1024]; \
    r2 = wp[(g) * 4096 + 2048]; r3 = wp[(g) * 4096 + 3072];
#define CONSG(r0, r1, r2, r3, g) \
    CONS1(r0, (g) * 4 + 0) CONS1(r1, (g) * 4 + 1) \
    CONS1(r2, (g) * 4 + 2) CONS1(r3, (g) * 4 + 3)

// ---- C: sequential recurrence, 1024 threads/block ----
// Round-9: round-8 phase-fused schedule with the s_w2aT stride bug fixed.
// W_h2att is [k=128][a=64]; its transpose rows are 128 long -> stride 136
// (272 B, 16B-aligned). Round 8's stride-72 rows overlapped and overran the
// array -> NaN from garbage LDS.
__global__ void __attribute__((amdgpu_flat_work_group_size(1024, 1024),
                               amdgpu_waves_per_eu(4, 4)))
kC(const float* __restrict__ FH,
   const float* __restrict__ W2a,
   const float* __restrict__ Walpha,
   const float* __restrict__ balpha,
   const float* __restrict__ bh2a) {
    __shared__ __align__(16) float s_val[256];   // [h(128) | att(128)]
    __shared__ float s_c[128];
    __shared__ float s_scratch[1024];            // dot partials only
    __shared__ float s_atth[64];
    __shared__ float s_scores[64];
    __shared__ float s_wgt[64];
    __shared__ float s_walpha[64];
    __shared__ float s_bh2a[64];
    __shared__ float s_penc[64 * 65];            // padded stride 65
    __shared__ __align__(16) bf16 s_encp[128 * 72];   // enc[d][s], stride 72 (16B rows)
    __shared__ __align__(16) bf16 s_w2aT[64 * 136];   // W2a^T [a][k(128)], stride 136

    int tid = threadIdx.x;
    int b = blockIdx.x;
    int kh = tid >> 9;            // K-half (0/1)
    int n  = tid & 511;           // gate output

    const uint4* wp = ((const uint4*)g_wpk2) + tid;

    float bias_r = g_bias[n];
    float bc_r   = bias_r + g_c0[n];      // bias + c0 (t>0)

    uint4 A0, A1, A2, A3, B0, B1, B2, B3;
    LOADG(A0, A1, A2, A3, 0)              // prologue: group 0 in flight

    if (tid < 256) s_val[tid] = 0.0f;
    if (tid < 128) s_c[tid] = 0.0f;
    if (tid < 64) { s_walpha[tid] = Walpha[tid]; s_bh2a[tid] = bh2a[tid]; }
    for (int i = tid; i < 64 * 64; i += 1024) {
        int s = i >> 6, a = i & 63;
        s_penc[s * 65 + a] = g_penc[((size_t)b * 64 + s) * 64 + a];
    }
    for (int i = tid; i < 128 * 64; i += 1024) {
        int d = i >> 6, s = i & 63;
        s_encp[d * 72 + s] = __float2bfloat16(FH[(size_t)b * 128 * 64 + i]);
        s_w2aT[s * 136 + d] = __float2bfloat16(W2a[i]);   // [a][k] transposed
    }
    float bal = balpha[0];

    const float* pre2p = g_pre2 + (size_t)b * TDIM * G4 + n;
    float* hattp = g_hatt + (size_t)b * TDIM * 256;

    for (int t = 0; t < TDIM; ++t) {
        __syncthreads();                       // s_val (h_{t-1}, att_{t-1}) ready
        float pre2v = (tid < 512) ? pre2p[(size_t)t * G4] : 0.0f;
        LOADG(B0, B1, B2, B3, 1)
        float acc0 = 0.f, acc1 = 0.f;
        const float4* vals = (const float4*)(s_val + kh * 128);
        CONSG(A0, A1, A2, A3, 0)               // A holds g0 (prefetched last iter)
        LOADG(A0, A1, A2, A3, 2)
        __builtin_amdgcn_sched_barrier(0);
        CONSG(B0, B1, B2, B3, 1)
        LOADG(B0, B1, B2, B3, 3)
        __builtin_amdgcn_sched_barrier(0);
        CONSG(A0, A1, A2, A3, 2)
        LOADG(A0, A1, A2, A3, 0)               // prefetch g0 for t+1 (hides under attn)
        __builtin_amdgcn_sched_barrier(0);
        CONSG(B0, B1, B2, B3, 3)
        // partial incl. pre2 + bias (+c0 for t>0), kh=0 side only
        s_scratch[tid] = acc0 + acc1 +
                         ((tid < 512) ? (pre2v + (t ? bc_r : bias_r)) : 0.0f);
        __syncthreads();
        // LSTM pointwise: read both K-half partials of all 4 gates directly
        if (tid < 128) {
            float gi = s_scratch[tid]       + s_scratch[tid + 512];
            float gf = s_scratch[tid + 128] + s_scratch[tid + 640];
            float gg = s_scratch[tid + 256] + s_scratch[tid + 768];
            float go = s_scratch[tid + 384] + s_scratch[tid + 896];
            float c = sigm(gf) * s_c[tid] + sigm(gi) * tanh_fast(gg);
            s_c[tid] = c;
            float h = sigm(go) * tanh_fast(c);
            s_val[tid] = h;
            hattp[(size_t)t * 256 + tid] = h;
        }
        __syncthreads();
        // att_h[a] = h @ W2a[:,a] + bh2a[a] : 16-lane group per a, shfl tree
        {
            int a = tid >> 4, sub = tid & 15;
            const float4* hv4 = (const float4*)s_val;
            float4 h0 = hv4[2 * sub], h1 = hv4[2 * sub + 1];
            uint4 wv = *(const uint4*)&s_w2aT[a * 136 + 8 * sub];
            float acc = bl(wv.x) * h0.x + bh(wv.x) * h0.y +
                        bl(wv.y) * h0.z + bh(wv.y) * h0.w +
                        bl(wv.z) * h1.x + bh(wv.z) * h1.y +
                        bl(wv.w) * h1.z + bh(wv.w) * h1.w;
            acc += __shfl_xor(acc, 1);
            acc += __shfl_xor(acc, 2);
            acc += __shfl_xor(acc, 4);
            acc += __shfl_xor(acc, 8);
            if (sub == 0) s_atth[a] = acc + s_bh2a[a];
        }
        __syncthreads();
        // scores[s] = sum_a tanh(p_enc + att_h) * W_alpha : 16 lanes per s
        {
            int ss = tid >> 4, sub = tid & 15;
            float acc = 0.f;
#pragma unroll
            for (int j = 0; j < 4; ++j) {
                int a = sub * 4 + j;
                float xv = s_penc[ss * 65 + a] + s_atth[a];
                acc += tanh_fast(xv) * s_walpha[a];
            }
            acc += __shfl_xor(acc, 1);
            acc += __shfl_xor(acc, 2);
            acc += __shfl_xor(acc, 4);
            acc += __shfl_xor(acc, 8);
            if (sub == 0) s_scores[ss] = acc + bal;
        }
        __syncthreads();
        if (tid < 64) {
            float v = s_scores[tid];
            float m = v;
#pragma unroll
            for (int off = 32; off > 0; off >>= 1) m = fmaxf(m, __shfl_xor(m, off));
            float e = __expf(v - m);
            float sum = e;
#pragma unroll
            for (int off = 32; off > 0; off >>= 1) sum += __shfl_xor(sum, off);
            s_wgt[tid] = e / sum;
        }
        __syncthreads();
        // att_res[d] = sum_s wgt[s] * enc[d][s] : 8-lane group per d, shfl tree
        {
            int d = tid >> 3, sub = tid & 7;
            uint4 ev = *(const uint4*)&s_encp[d * 72 + 8 * sub];
            int s0 = 8 * sub;
            float acc = bl(ev.x) * s_wgt[s0]     + bh(ev.x) * s_wgt[s0 + 1] +
                        bl(ev.y) * s_wgt[s0 + 2] + bh(ev.y) * s_wgt[s0 + 3] +
                        bl(ev.z) * s_wgt[s0 + 4] + bh(ev.z) * s_wgt[s0 + 5] +
                        bl(ev.w) * s_wgt[s0 + 6] + bh(ev.w) * s_wgt[s0 + 7];
            acc += __shfl_xor(acc, 1);
            acc += __shfl_xor(acc, 2);
            acc += __shfl_xor(acc, 4);
            if (sub == 0) {
                s_val[128 + d] = acc;
                hattp[(size_t)t * 256 + 128 + d] = acc;
            }
        }
        // loop-top barrier covers s_val/s_scratch reuse
    }
}

// ---- D: final out = [h|att] @ (W_aap@W_out) + bao ----
__global__ void kD(float* __restrict__ out) {
    int r = blockIdx.x, lane = threadIdx.x;
    const float4* hv = (const float4*)(g_hatt + (size_t)r * 256);
    float4 v = hv[lane];
    int k0 = lane * 4;
    float acc[5];
#pragma unroll
    for (int o = 0; o < 5; ++o)
        acc[o] = v.x * g_Wao[(k0 + 0) * 5 + o] + v.y * g_Wao[(k0 + 1) * 5 + o] +
                 v.z * g_Wao[(k0 + 2) * 5 + o] + v.w * g_Wao[(k0 + 3) * 5 + o];
#pragma unroll
    for (int off = 32; off > 0; off >>= 1) {
#pragma unroll
        for (int o = 0; o < 5; ++o) acc[o] += __shfl_xor(acc[o], off);
    }
    if (lane == 0) {
#pragma unroll
        for (int o = 0; o < 5; ++o) out[(size_t)r * 5 + o] = acc[o] + g_bao[o];
    }
}

extern "C" void kernel_launch(void* const* d_in, const int* in_sizes, int n_in,
                              void* d_out, int out_size, void* d_ws, size_t ws_size,
                              hipStream_t stream) {
    (void)in_sizes; (void)n_in; (void)d_ws; (void)ws_size; (void)out_size;
    const float* tok  = (const float*)d_in[0];
    const float* feat = (const float*)d_in[1];
    const float* FH   = (const float*)d_in[2];
    const float* Wemb = (const float*)d_in[3];
    const float* bemb = (const float*)d_in[4];
    const float* Wih  = (const float*)d_in[5];
    const float* bih  = (const float*)d_in[6];
    const float* Whh  = (const float*)d_in[7];
    const float* bhh  = (const float*)d_in[8];
    const float* W2a  = (const float*)d_in[9];
    const float* bh2a = (const float*)d_in[10];
    const float* Wal  = (const float*)d_in[11];
    const float* bal  = (const float*)d_in[12];
    const float* Wep  = (const float*)d_in[13];
    const float* bep  = (const float*)d_in[14];
    const float* Waap = (const float*)d_in[15];
    const float* baap = (const float*)d_in[16];
    const float* Wout = (const float*)d_in[17];
    const float* bout = (const float*)d_in[18];
    float* out = (float*)d_out;

    kA1<<<dim3(BT / 4), dim3(256), 0, stream>>>(tok, feat, Wemb, bemb);
    kA2a<<<dim3(128), dim3(512), 0, stream>>>(Wih, Whh, Waap);
    kA2c<<<dim3(1), dim3(512), 0, stream>>>(bih, bhh, Wih, Waap, baap, Wout, bout);
    kA2d<<<dim3(64), dim3(256), 0, stream>>>(FH, Wep, bep);
    kB<<<dim3(BT / 8), dim3(512), 0, stream>>>(Wih);
    kC<<<dim3(64), dim3(1024), 0, stream>>>(FH, W2a, Wal, bal, bh2a);
    kD<<<dim3(BT), dim3(64), 0, stream>>>(out);
}

// Round 10
// 1814.607 us; speedup vs baseline: 2.1217x; 1.0188x over previous
//
#include <hip/hip_runtime.h>
#include <hip/hip_bf16.h>

#define BDIM 64
#define TDIM 360
#define BT (BDIM*TDIM)        // 23040
#define CDIM 128
#define HWSZ 1024
#define SDIM 64
#define G4 512
#define KTOP 160

typedef __hip_bfloat16 bf16;

static __device__ __forceinline__ unsigned int f2bu(float x) {
    bf16 b = __float2bfloat16(x);
    unsigned short u; __builtin_memcpy(&u, &b, 2); return (unsigned int)u;
}
static __device__ __forceinline__ float b2f(bf16 x) { return __bfloat162float(x); }
static __device__ __forceinline__ float bl(unsigned int u) { return __uint_as_float(u << 16); }
static __device__ __forceinline__ float bh(unsigned int u) { return __uint_as_float(u & 0xffff0000u); }
static __device__ __forceinline__ float tanh_fast(float x) {
    float e = __expf(2.0f * x);
    return 1.0f - 2.0f / (e + 1.0f);
}
static __device__ __forceinline__ float sigm(float x) {
    return 1.0f / (1.0f + __expf(-x));
}

// ---- static device workspace ----
__device__ float        g_ArowsF[BT * KTOP];   // [x_emb(32) | in_seq(128)] fp32
__device__ float        g_pre2[BT * G4];       // precomputed non-recurrent gate part
// folded recurrent weights, bf16 pairs, streaming layout:
// uint4 index jblk*1024 + u ; u = kh*512 + n ; covers K-pairs kh*64+jblk*4+{0..3}
__device__ __align__(16) unsigned int g_wpk2[16 * 1024 * 4];
__device__ float        g_penc[BDIM * SDIM * 64];
__device__ float        g_hatt[BT * 256];      // [h(128) | att(128)] per (b,t)
__device__ float        g_Wao[256 * 5];
__device__ float        g_bao[5];
__device__ float        g_bias[G4];
__device__ float        g_c0[G4];

// ---- A1: build [x_emb | gathered feature] rows ----
__global__ void kA1(const float* __restrict__ tok, const float* __restrict__ feat,
                    const float* __restrict__ Wemb, const float* __restrict__ bemb) {
    int row  = blockIdx.x * 4 + (threadIdx.x >> 6);
    int lane = threadIdx.x & 63;
    const float* tp = tok + (size_t)row * 4;
    float t0 = tp[0], t1 = tp[1], t2 = tp[2], t3 = tp[3];
    int b = row / TDIM;
    int x = (int)(t0 * 100.0f);
    int y = (int)(t1 * 100.0f);
    x = min(max(x, 0), 31);
    y = min(max(y, 0), 31);
    int idx = y * 32 + x;
    float* out = g_ArowsF + (size_t)row * KTOP;
    if (lane < 32) {
        float e = t0 * Wemb[lane] + t1 * Wemb[32 + lane] +
                  t2 * Wemb[64 + lane] + t3 * Wemb[96 + lane] + bemb[lane];
        out[lane] = e;
    }
    const float* fb = feat + (size_t)b * CDIM * HWSZ + idx;
    out[32 + lane]      = fb[(size_t)lane * HWSZ];
    out[32 + 64 + lane] = fb[(size_t)(64 + lane) * HWSZ];
}

// ---- A2a: fold recurrent weights into streaming layout ----
__global__ void kA2a(const float* __restrict__ Wih, const float* __restrict__ Whh,
                     const float* __restrict__ Waap) {
    __shared__ float sa0[128], sa1[128];
    int p = blockIdx.x, n = threadIdx.x;
    int r0 = 2 * p, r1 = 2 * p + 1;
    if (n < 128)            sa0[n]        = Waap[r0 * 128 + n];
    else if (n < 256)       sa1[n - 128]  = Waap[r1 * 128 + (n - 128)];
    __syncthreads();
    float acc0 = (r0 < 128) ? Whh[r0 * G4 + n] : 0.0f;
    float acc1 = (r1 < 128) ? Whh[r1 * G4 + n] : 0.0f;
    for (int j = 0; j < 128; ++j) {
        float wi = Wih[(160 + j) * G4 + n];
        acc0 += sa0[j] * wi;
        acc1 += sa1[j] * wi;
    }
    int kh = p >> 6, j = p & 63;
    int jblk = j >> 2, jj = j & 3;
    int u = kh * 512 + n;
    g_wpk2[((size_t)jblk * 1024 + u) * 4 + jj] = f2bu(acc0) | (f2bu(acc1) << 16);
}

// ---- A2c: bias vectors, c0, Wao, bao ----
__global__ void kA2c(const float* __restrict__ bih, const float* __restrict__ bhh,
                     const float* __restrict__ Wih, const float* __restrict__ Waap,
                     const float* __restrict__ baap, const float* __restrict__ Wout,
                     const float* __restrict__ bout) {
    __shared__ float sb[128];
    int n = threadIdx.x;
    if (n < 128) sb[n] = baap[n];
    __syncthreads();
    g_bias[n] = bih[n] + bhh[n];
    float c0 = 0.0f;
    for (int j = 0; j < 128; ++j) c0 += sb[j] * Wih[(160 + j) * G4 + n];
    g_c0[n] = c0;
    if (n < 256) {
        for (int o = 0; o < 5; ++o) {
            float acc = 0.0f;
            for (int j = 0; j < 128; ++j) acc += Waap[n * 128 + j] * Wout[j * 5 + o];
            g_Wao[n * 5 + o] = acc;
        }
    }
    if (n == 0) {
        for (int o = 0; o < 5; ++o) {
            float acc = bout[o];
            for (int j = 0; j < 128; ++j) acc += sb[j] * Wout[j * 5 + o];
            g_bao[o] = acc;
        }
    }
}

// ---- A2d: p_enc ----
__global__ void kA2d(const float* __restrict__ FH, const float* __restrict__ Wep,
                     const float* __restrict__ bep) {
    __shared__ float sfh[128 * 64];
    int b = blockIdx.x, tid = threadIdx.x;
    for (int i = tid; i < 128 * 64; i += 256) sfh[i] = FH[(size_t)b * 128 * 64 + i];
    __syncthreads();
    int a = tid & 63, sg = tid >> 6;
    float bias = bep[a];
    float acc[16];
#pragma unroll
    for (int i = 0; i < 16; ++i) acc[i] = bias;
    for (int d = 0; d < 128; ++d) {
        float wa = Wep[d * 64 + a];
#pragma unroll
        for (int i = 0; i < 16; ++i) acc[i] += sfh[d * 64 + sg * 16 + i] * wa;
    }
    for (int i = 0; i < 16; ++i)
        g_penc[((size_t)b * 64 + sg * 16 + i) * 64 + a] = acc[i];
}

// ---- B: pre2 = Arows @ W_ih[0:160] ----
__global__ void __attribute__((amdgpu_flat_work_group_size(512, 512),
                               amdgpu_waves_per_eu(2, 2)))
kB(const float* __restrict__ Wih) {
    int n = threadIdx.x;
    int m0 = blockIdx.x * 8;
    float racc[8];
#pragma unroll
    for (int r = 0; r < 8; ++r) racc[r] = 0.0f;
#pragma unroll 1
    for (int pass = 0; pass < 2; ++pass) {
        float wcol[80];
#pragma unroll
        for (int j = 0; j < 80; ++j) wcol[j] = Wih[(pass * 80 + j) * G4 + n];
#pragma unroll
        for (int r = 0; r < 8; ++r) {
            const float4* rp = (const float4*)(g_ArowsF + (size_t)(m0 + r) * KTOP + pass * 80);
            float a0 = 0.f, a1 = 0.f, a2 = 0.f, a3 = 0.f;
#pragma unroll
            for (int q = 0; q < 20; ++q) {
                float4 v = rp[q];
                a0 += wcol[4 * q + 0] * v.x;
                a1 += wcol[4 * q + 1] * v.y;
                a2 += wcol[4 * q + 2] * v.z;
                a3 += wcol[4 * q + 3] * v.w;
            }
            racc[r] += (a0 + a1) + (a2 + a3);
        }
    }
#pragma unroll
    for (int r = 0; r < 8; ++r)
        g_pre2[(size_t)(m0 + r) * G4 + n] = racc[r];
}

// Consume one uint4 (4 K-pairs) against vals[2jb],[2jb+1] (vals = s_val base, jb 0..31).
#define CONS1(W, jb) { \
    float4 v0 = vals[2 * (jb)], v1 = vals[2 * (jb) + 1]; \
    acc0 += bl(W.x) * v0.x;  acc1 += bh(W.x) * v0.y; \
    acc0 += bl(W.y) * v0.z;  acc1 += bh(W.y) * v0.w; \
    acc0 += bl(W.z) * v1.x;  acc1 += bh(W.z) * v1.y; \
    acc0 += bl(W.w) * v1.z;  acc1 += bh(W.w) * v1.w; }
#define LDP(R, jb)  R = wp[(jb) * 1024];          // kh=0 half (vs h)
#define LDQ(R, jb)  R = wp[(jb) * 1024 + 512];    // kh=1 half (vs att)
#define SB __builtin_amdgcn_sched_barrier(0);

// ---- C: sequential recurrence, 512 threads/block, thread = gate n ----
// Round-10: 512-thr block -> 128-VGPR budget (round-2 evidence). 16 weight
// uint4s (P, h-half) prefetched at end of each dot, landing during pw+tail;
// dot consumes P immediately and streams the att-half (Q) in 4 pipelined
// tranches. Exposed L2 stream halves; gate-combine phase gone (thread owns
// full K=256) -> 6 barriers/step at 8 waves (was 7 at 16 waves).
__global__ void __launch_bounds__(512) kC(const float* __restrict__ FH,
                                          const float* __restrict__ W2a,
                                          const float* __restrict__ Walpha,
                                          const float* __restrict__ balpha,
                                          const float* __restrict__ bh2a) {
    __shared__ __align__(16) float s_val[256];   // [h(128) | att(128)]
    __shared__ float s_c[128];
    __shared__ float s_gates[512];
    __shared__ float s_atth[64];
    __shared__ float s_scores[64];
    __shared__ float s_wgt[64];
    __shared__ float s_walpha[64];
    __shared__ float s_bh2a[64];
    __shared__ float s_penc[64 * 65];                 // padded stride 65
    __shared__ __align__(16) bf16 s_encp[128 * 72];   // enc[d][s], stride 72
    __shared__ __align__(16) bf16 s_w2aT[64 * 136];   // W2a^T [a][k(128)], stride 136

    int tid = threadIdx.x;
    int b = blockIdx.x;
    int n = tid;                                 // gate output, full K

    const uint4* wp = ((const uint4*)g_wpk2) + n;

    uint4 P0,P1,P2,P3,P4,P5,P6,P7,P8,P9,P10,P11,P12,P13,P14,P15;
    // prologue: h-half weights in flight (land during LDS init)
    LDP(P0,0)  LDP(P1,1)  LDP(P2,2)  LDP(P3,3)
    LDP(P4,4)  LDP(P5,5)  LDP(P6,6)  LDP(P7,7)
    LDP(P8,8)  LDP(P9,9)  LDP(P10,10) LDP(P11,11)
    LDP(P12,12) LDP(P13,13) LDP(P14,14) LDP(P15,15)
    SB

    float bias_r = g_bias[n];
    float bc_r   = bias_r + g_c0[n];      // bias + c0 (t>0)

    if (tid < 256) s_val[tid] = 0.0f;
    if (tid < 128) s_c[tid] = 0.0f;
    if (tid < 64) { s_walpha[tid] = Walpha[tid]; s_bh2a[tid] = bh2a[tid]; }
    for (int i = tid; i < 64 * 64; i += 512) {
        int s = i >> 6, a = i & 63;
        s_penc[s * 65 + a] = g_penc[((size_t)b * 64 + s) * 64 + a];
    }
    for (int i = tid; i < 128 * 64; i += 512) {
        int d = i >> 6, s = i & 63;
        s_encp[d * 72 + s] = __float2bfloat16(FH[(size_t)b * 128 * 64 + i]);
        s_w2aT[s * 136 + d] = __float2bfloat16(W2a[i]);   // [a][k] transposed
    }
    float bal = balpha[0];

    const float* pre2p = g_pre2 + (size_t)b * TDIM * G4 + n;
    float* hattp = g_hatt + (size_t)b * TDIM * 256;

    for (int t = 0; t < TDIM; ++t) {
        __syncthreads();                 // (1) s_val state(t-1) ready
        float pre2v = pre2p[(size_t)t * G4];
        float acc0 = 0.f, acc1 = 0.f;
        const float4* vals = (const float4*)s_val;
        uint4 Q0,Q1,Q2,Q3,Q4,Q5,Q6,Q7,Q8,Q9,Q10,Q11,Q12,Q13,Q14,Q15;
        // tranche-pipelined: issue Q group k+? while consuming prefetched P
        LDQ(Q0,0)  LDQ(Q1,1)  LDQ(Q2,2)  LDQ(Q3,3)
        CONS1(P0,0)  CONS1(P1,1)  CONS1(P2,2)  CONS1(P3,3)
        SB
        LDQ(Q4,4)  LDQ(Q5,5)  LDQ(Q6,6)  LDQ(Q7,7)
        CONS1(P4,4)  CONS1(P5,5)  CONS1(P6,6)  CONS1(P7,7)
        SB
        LDQ(Q8,8)  LDQ(Q9,9)  LDQ(Q10,10) LDQ(Q11,11)
        CONS1(P8,8)  CONS1(P9,9)  CONS1(P10,10) CONS1(P11,11)
        SB
        LDQ(Q12,12) LDQ(Q13,13) LDQ(Q14,14) LDQ(Q15,15)
        CONS1(P12,12) CONS1(P13,13) CONS1(P14,14) CONS1(P15,15)
        SB
        CONS1(Q0,16)  CONS1(Q1,17)  CONS1(Q2,18)  CONS1(Q3,19)
        CONS1(Q4,20)  CONS1(Q5,21)  CONS1(Q6,22)  CONS1(Q7,23)
        CONS1(Q8,24)  CONS1(Q9,25)  CONS1(Q10,26) CONS1(Q11,27)
        CONS1(Q12,28) CONS1(Q13,29) CONS1(Q14,30) CONS1(Q15,31)
        s_gates[n] = acc0 + acc1 + pre2v + (t ? bc_r : bias_r);
        SB
        // prefetch h-half for t+1: lands during pw + tail below
        LDP(P0,0)  LDP(P1,1)  LDP(P2,2)  LDP(P3,3)
        LDP(P4,4)  LDP(P5,5)  LDP(P6,6)  LDP(P7,7)
        LDP(P8,8)  LDP(P9,9)  LDP(P10,10) LDP(P11,11)
        LDP(P12,12) LDP(P13,13) LDP(P14,14) LDP(P15,15)
        SB
        __syncthreads();                 // (2) gates ready
        // LSTM pointwise (gate order i,f,g,o)
        if (tid < 128) {
            float gi = s_gates[tid];
            float gf = s_gates[tid + 128];
            float gg = s_gates[tid + 256];
            float go = s_gates[tid + 384];
            float c = sigm(gf) * s_c[tid] + sigm(gi) * tanh_fast(gg);
            s_c[tid] = c;
            float h = sigm(go) * tanh_fast(c);
            s_val[tid] = h;
            hattp[(size_t)t * 256 + tid] = h;
        }
        __syncthreads();                 // (3) h ready
        // att_h[a] = h @ W2a[:,a] + bh2a[a] : 8-lane group per a
        {
            int a = tid >> 3, sub = tid & 7;
            const float4* hv4 = (const float4*)s_val;
            float4 h0 = hv4[4 * sub], h1 = hv4[4 * sub + 1],
                   h2 = hv4[4 * sub + 2], h3 = hv4[4 * sub + 3];
            uint4 w0 = *(const uint4*)&s_w2aT[a * 136 + 16 * sub];
            uint4 w1 = *(const uint4*)&s_w2aT[a * 136 + 16 * sub + 8];
            float acc = bl(w0.x) * h0.x + bh(w0.x) * h0.y +
                        bl(w0.y) * h0.z + bh(w0.y) * h0.w +
                        bl(w0.z) * h1.x + bh(w0.z) * h1.y +
                        bl(w0.w) * h1.z + bh(w0.w) * h1.w +
                        bl(w1.x) * h2.x + bh(w1.x) * h2.y +
                        bl(w1.y) * h2.z + bh(w1.y) * h2.w +
                        bl(w1.z) * h3.x + bh(w1.z) * h3.y +
                        bl(w1.w) * h3.z + bh(w1.w) * h3.w;
            acc += __shfl_xor(acc, 1);
            acc += __shfl_xor(acc, 2);
            acc += __shfl_xor(acc, 4);
            if (sub == 0) s_atth[a] = acc + s_bh2a[a];
        }
        __syncthreads();                 // (4) atth ready
        // scores[s] = sum_a tanh(p_enc + att_h) * W_alpha : 8 lanes per s
        {
            int ss = tid >> 3, sub = tid & 7;
            float acc = 0.f;
#pragma unroll
            for (int j = 0; j < 8; ++j) {
                int a = sub * 8 + j;
                float xv = s_penc[ss * 65 + a] + s_atth[a];
                acc += tanh_fast(xv) * s_walpha[a];
            }
            acc += __shfl_xor(acc, 1);
            acc += __shfl_xor(acc, 2);
            acc += __shfl_xor(acc, 4);
            if (sub == 0) s_scores[ss] = acc + bal;
        }
        __syncthreads();                 // (5) scores ready
        if (tid < 64) {
            float v = s_scores[tid];
            float m = v;
#pragma unroll
            for (int off = 32; off > 0; off >>= 1) m = fmaxf(m, __shfl_xor(m, off));
            float e = __expf(v - m);
            float sum = e;
#pragma unroll
            for (int off = 32; off > 0; off >>= 1) sum += __shfl_xor(sum, off);
            s_wgt[tid] = e / sum;
        }
        __syncthreads();                 // (6) wgt ready
        // att_res[d] = sum_s wgt[s] * enc[d][s] : 4-lane group per d
        {
            int d = tid >> 2, sub = tid & 3;
            uint4 e0 = *(const uint4*)&s_encp[d * 72 + 16 * sub];
            uint4 e1 = *(const uint4*)&s_encp[d * 72 + 16 * sub + 8];
            int s0 = 16 * sub;
            float acc = bl(e0.x) * s_wgt[s0]      + bh(e0.x) * s_wgt[s0 + 1] +
                        bl(e0.y) * s_wgt[s0 + 2]  + bh(e0.y) * s_wgt[s0 + 3] +
                        bl(e0.z) * s_wgt[s0 + 4]  + bh(e0.z) * s_wgt[s0 + 5] +
                        bl(e0.w) * s_wgt[s0 + 6]  + bh(e0.w) * s_wgt[s0 + 7] +
                        bl(e1.x) * s_wgt[s0 + 8]  + bh(e1.x) * s_wgt[s0 + 9] +
                        bl(e1.y) * s_wgt[s0 + 10] + bh(e1.y) * s_wgt[s0 + 11] +
                        bl(e1.z) * s_wgt[s0 + 12] + bh(e1.z) * s_wgt[s0 + 13] +
                        bl(e1.w) * s_wgt[s0 + 14] + bh(e1.w) * s_wgt[s0 + 15];
            acc += __shfl_xor(acc, 1);
            acc += __shfl_xor(acc, 2);
            if (sub == 0) {
                s_val[128 + d] = acc;
                hattp[(size_t)t * 256 + 128 + d] = acc;
            }
        }
        // loop-top barrier covers s_val/s_gates reuse
    }
}

// ---- D: final out = [h|att] @ (W_aap@W_out) + bao ----
__global__ void kD(float* __restrict__ out) {
    int r = blockIdx.x, lane = threadIdx.x;
    const float4* hv = (const float4*)(g_hatt + (size_t)r * 256);
    float4 v = hv[lane];
    int k0 = lane * 4;
    float acc[5];
#pragma unroll
    for (int o = 0; o < 5; ++o)
        acc[o] = v.x * g_Wao[(k0 + 0) * 5 + o] + v.y * g_Wao[(k0 + 1) * 5 + o] +
                 v.z * g_Wao[(k0 + 2) * 5 + o] + v.w * g_Wao[(k0 + 3) * 5 + o];
#pragma unroll
    for (int off = 32; off > 0; off >>= 1) {
#pragma unroll
        for (int o = 0; o < 5; ++o) acc[o] += __shfl_xor(acc[o], off);
    }
    if (lane == 0) {
#pragma unroll
        for (int o = 0; o < 5; ++o) out[(size_t)r * 5 + o] = acc[o] + g_bao[o];
    }
}

extern "C" void kernel_launch(void* const* d_in, const int* in_sizes, int n_in,
                              void* d_out, int out_size, void* d_ws, size_t ws_size,
                              hipStream_t stream) {
    (void)in_sizes; (void)n_in; (void)d_ws; (void)ws_size; (void)out_size;
    const float* tok  = (const float*)d_in[0];
    const float* feat = (const float*)d_in[1];
    const float* FH   = (const float*)d_in[2];
    const float* Wemb = (const float*)d_in[3];
    const float* bemb = (const float*)d_in[4];
    const float* Wih  = (const float*)d_in[5];
    const float* bih  = (const float*)d_in[6];
    const float* Whh  = (const float*)d_in[7];
    const float* bhh  = (const float*)d_in[8];
    const float* W2a  = (const float*)d_in[9];
    const float* bh2a = (const float*)d_in[10];
    const float* Wal  = (const float*)d_in[11];
    const float* bal  = (const float*)d_in[12];
    const float* Wep  = (const float*)d_in[13];
    const float* bep  = (const float*)d_in[14];
    const float* Waap = (const float*)d_in[15];
    const float* baap = (const float*)d_in[16];
    const float* Wout = (const float*)d_in[17];
    const float* bout = (const float*)d_in[18];
    float* out = (float*)d_out;

    kA1<<<dim3(BT / 4), dim3(256), 0, stream>>>(tok, feat, Wemb, bemb);
    kA2a<<<dim3(128), dim3(512), 0, stream>>>(Wih, Whh, Waap);
    kA2c<<<dim3(1), dim3(512), 0, stream>>>(bih, bhh, Wih, Waap, baap, Wout, bout);
    kA2d<<<dim3(64), dim3(256), 0, stream>>>(FH, Wep, bep);
    kB<<<dim3(BT / 8), dim3(512), 0, stream>>>(Wih);
    kC<<<dim3(64), dim3(512), 0, stream>>>(FH, W2a, Wal, bal, bh2a);
    kD<<<dim3(BT), dim3(64), 0, stream>>>(out);
}